// Round 4
// baseline (237.675 us; speedup 1.0000x reference)
//
#include <hip/hip_runtime.h>

#define BB 8
#define NN 4096
#define CCH 512
#define KK 32
#define CLS 21
#define BN_EPS 1e-3f

#define TPB 512
#define CHUNK 64
#define NBLK (NN / CHUNK)   // 64 -> grid 512 blocks = 2/CU

typedef _Float16 f16;
typedef _Float16 half2v __attribute__((ext_vector_type(2)));
typedef _Float16 half4v __attribute__((ext_vector_type(4)));
typedef _Float16 half8v __attribute__((ext_vector_type(8)));
typedef float float2v __attribute__((ext_vector_type(2)));

// xn pitch in f16 units (1056 B, 16B-aligned)
#define XPH 528
#define WPH 40

// LDS carve (bytes): cwL 32768 | xn 33792 | wt 2560 | f32 tail
#define SMB_CWL 0
#define SMB_XN  32768
#define SMB_WT  (SMB_XN + 32 * XPH * 2)      // 66560
#define SMB_F32 (SMB_WT + 32 * WPH * 2)      // 69120
#define SM_BYTES (SMB_F32 + (64 + 256 + 32 + 32) * 4)

// ws layout (floats)
#define WS_WX   0
#define WS_WSUM (BB * CCH * KK)              // 131072
#define WS_ENC  (WS_WSUM + BB * KK)          // 131328
#define WS_ATTN (WS_ENC + BB * CCH)          // 135424

template <int CTRL>
__device__ __forceinline__ float dpp_add(float v) {
    int r = __builtin_amdgcn_update_dpp(0, __builtin_bit_cast(int, v),
                                        CTRL, 0xF, 0xF, true);
    return v + __builtin_bit_cast(float, r);
}
__device__ __forceinline__ float rowsum16(float v) {
    v = dpp_add<0x128>(v);
    v = dpp_add<0x124>(v);
    v = dpp_add<0x122>(v);
    v = dpp_add<0x121>(v);
    return v;
}

__device__ __forceinline__ float dot8f(half8v a, half8v b, float c) {
#if __has_builtin(__builtin_amdgcn_fdot2)
    half2v a0 = {a[0], a[1]}, b0 = {b[0], b[1]};
    half2v a1 = {a[2], a[3]}, b1 = {b[2], b[3]};
    half2v a2 = {a[4], a[5]}, b2 = {b[4], b[5]};
    half2v a3 = {a[6], a[7]}, b3 = {b[6], b[7]};
    c = __builtin_amdgcn_fdot2(a0, b0, c, false);
    c = __builtin_amdgcn_fdot2(a1, b1, c, false);
    c = __builtin_amdgcn_fdot2(a2, b2, c, false);
    c = __builtin_amdgcn_fdot2(a3, b3, c, false);
    return c;
#else
#pragma unroll
    for (int i = 0; i < 8; ++i) c += (float)a[i] * (float)b[i];
    return c;
#endif
}

// ---------------------------------------------------------------------------
// Kernel A: fused cross -> softmax -> wx partials. 512 thr, 2 blocks/CU.
// NOTE: __launch_bounds__ 2nd arg empirically acts as blocks/CU here:
//   (512,2) -> 128 VGPR cap (r2), (512,4) -> 64 VGPR cap + spills (r3).
// B2 map: cpart=t&15, kg=(t>>4)&3 (k=kg+4j), wave w=t>>6 owns rows 4w..4w+3
// C  map: kq=t&7 (k=kq*4..+3), cg=t>>3 (c=cg*8..+7), all 32 rows
// ---------------------------------------------------------------------------
__global__ __launch_bounds__(TPB, 2) void enc_partial(
    const float* __restrict__ x, const float* __restrict__ cw,
    const float* __restrict__ sf, float* __restrict__ ws)
{
    extern __shared__ char smraw[];
    f16*   cwL  = (f16*)(smraw + SMB_CWL);
    f16*   xn   = (f16*)(smraw + SMB_XN);
    f16*   wt   = (f16*)(smraw + SMB_WT);
    float* xsqp = (float*)(smraw + SMB_F32);          // [8 waves][8 rows]
    float* wsp  = xsqp + 64;                          // [8][32] scratch / wsum partials
    float* cwsqL = wsp + 256;                         // [32]
    float* nsfL  = cwsqL + 32;                        // [32]

    const int t = threadIdx.x;
    const int b = blockIdx.y;
    const int w = t >> 6;
    const int l = t & 63;
    const int cpart = t & 15;
    const int kg    = (t >> 4) & 3;

    // ---- build cwL: cwL[s*8+j][lane][e] = cw[(l>>4)&3 + 4j][(l&15)*8 + s*128 + e] ----
    {
        for (int pi = 0; pi < 4; ++pi) {
            const int pair = w * 4 + pi;        // 0..31
            const int s = pair >> 3, j = pair & 7;
            const int k = ((l >> 4) & 3) + 4 * j;
            half8v v;
#pragma unroll
            for (int e = 0; e < 8; ++e) {
                const int c = (l & 15) * 8 + s * 128 + e;
                v[e] = (f16)cw[c * KK + k];
            }
            *reinterpret_cast<half8v*>(cwL + ((size_t)pair * 64 + l) * 8) = v;
        }
    }
    // ---- cwsq partials ----
    if (t < 256) {
        const int k = t & 31, part = t >> 5;
        float s = 0.f;
        for (int c = part * 64; c < part * 64 + 64; ++c) {
            const float v = cw[c * KK + k];
            s += v * v;
        }
        wsp[part * 32 + k] = s;
    }
    __syncthreads();
    if (t < 32) {
        float s = 0.f;
#pragma unroll
        for (int p = 0; p < 8; ++p) s += wsp[p * 32 + t];
        cwsqL[t] = s;
        nsfL[t]  = -sf[t];
    }
    __syncthreads();

    const int kq = t & 7;
    const int cg = t >> 3;    // 0..63, c-oct = cg*8

    float2v acc2[4][4];
#pragma unroll
    for (int p = 0; p < 4; ++p)
#pragma unroll
        for (int k = 0; k < 4; ++k) acc2[p][k] = (float2v){0.f, 0.f};
    float wsacc[8] = {0.f, 0.f, 0.f, 0.f, 0.f, 0.f, 0.f, 0.f};

    const int n0base = blockIdx.x * CHUNK;
    for (int tile = 0; tile < CHUNK / 32; ++tile) {
        const int n0 = n0base + tile * 32;

        // ---- stage 32x512 fp32 -> f16 LDS; exact fp32 x_sq on the fly ----
        {
            float sqp[8];
#pragma unroll
            for (int i = 0; i < 8; ++i) {
                const int f  = i * TPB + t;
                const int rr = f >> 7;
                const int c4 = (f & 127) << 2;
                const float4 v = *reinterpret_cast<const float4*>(
                    x + (size_t)(b * NN + n0 + rr) * CCH + c4);
                sqp[i] = v.x * v.x + v.y * v.y + v.z * v.z + v.w * v.w;
                half4v h = {(f16)v.x, (f16)v.y, (f16)v.z, (f16)v.w};
                *reinterpret_cast<half4v*>(xn + rr * XPH + c4) = h;
            }
#pragma unroll
            for (int i = 0; i < 8; ++i) {
                float v = sqp[i];
                v += __shfl_xor(v, 1);  v += __shfl_xor(v, 2);
                v += __shfl_xor(v, 4);  v += __shfl_xor(v, 8);
                v += __shfl_xor(v, 16); v += __shfl_xor(v, 32);
                if (l == 0) xsqp[w * 8 + i] = v;   // row = 4i + (w>>1)
            }
        }
        __syncthreads();

        // ---- B2: cross via fdot2; wave w handles rows 4w..4w+3 ----
        float cr[4][8];
#pragma unroll
        for (int q = 0; q < 4; ++q)
#pragma unroll
            for (int j = 0; j < 8; ++j) cr[q][j] = 0.f;

        for (int s = 0; s < 4; ++s) {
            half8v xv[4];
#pragma unroll
            for (int q = 0; q < 4; ++q)
                xv[q] = *reinterpret_cast<const half8v*>(
                    xn + (w * 4 + q) * XPH + s * 128 + cpart * 8);
#pragma unroll
            for (int j = 0; j < 8; ++j) {
                const half8v cv = *reinterpret_cast<const half8v*>(
                    cwL + ((size_t)(s * 8 + j) * 64 + l) * 8);
#pragma unroll
                for (int q = 0; q < 4; ++q) cr[q][j] = dot8f(xv[q], cv, cr[q][j]);
            }
        }
#pragma unroll
        for (int q = 0; q < 4; ++q)
#pragma unroll
            for (int j = 0; j < 8; ++j) cr[q][j] = rowsum16(cr[q][j]);

        // ---- softmax over 32 k (nsf/cq live only here, from LDS) ----
        {
            float nsf[8], cq[8];
#pragma unroll
            for (int j = 0; j < 8; ++j) {
                nsf[j] = nsfL[kg + 4 * j];
                cq[j]  = cwsqL[kg + 4 * j];
            }
#pragma unroll
            for (int q = 0; q < 4; ++q) {
                const int r = w * 4 + q;
                const float xs = xsqp[(2 * (r & 3)) * 8 + (r >> 2)]
                               + xsqp[(2 * (r & 3) + 1) * 8 + (r >> 2)];
                float lg[8];
#pragma unroll
                for (int j = 0; j < 8; ++j)
                    lg[j] = (xs - 2.f * cr[q][j] + cq[j]) * nsf[j];
                float m = lg[0];
#pragma unroll
                for (int j = 1; j < 8; ++j) m = fmaxf(m, lg[j]);
                m = fmaxf(m, __shfl_xor(m, 16));
                m = fmaxf(m, __shfl_xor(m, 32));
                float e[8], ssum = 0.f;
#pragma unroll
                for (int j = 0; j < 8; ++j) { e[j] = __expf(lg[j] - m); ssum += e[j]; }
                ssum += __shfl_xor(ssum, 16);
                ssum += __shfl_xor(ssum, 32);
                const float inv = 1.f / ssum;
                if (cpart == 0) {
#pragma unroll
                    for (int j = 0; j < 8; ++j) {
                        const float wv = e[j] * inv;
                        wsacc[j] += wv;
                        wt[r * WPH + kg + 4 * j] = (f16)wv;
                    }
                }
            }
        }
        __syncthreads();   // wt ready

        // ---- C: wx[c][k] += w[n][k]*x[n][c], 8c x 4k per thread, all 32 rows ----
#pragma unroll 4
        for (int rr = 0; rr < 32; ++rr) {
            const half8v xv = *reinterpret_cast<const half8v*>(xn + rr * XPH + cg * 8);
            const half4v wv = *reinterpret_cast<const half4v*>(wt + rr * WPH + kq * 4);
            const float wk0 = (float)wv[0], wk1 = (float)wv[1];
            const float wk2 = (float)wv[2], wk3 = (float)wv[3];
#pragma unroll
            for (int p = 0; p < 4; ++p) {
                const float2v xf = {(float)xv[2 * p], (float)xv[2 * p + 1]};
                acc2[p][0] += xf * (float2v){wk0, wk0};
                acc2[p][1] += xf * (float2v){wk1, wk1};
                acc2[p][2] += xf * (float2v){wk2, wk2};
                acc2[p][3] += xf * (float2v){wk3, wk3};
            }
        }
        __syncthreads();   // protect xn/wt before next tile
    }

    // ---- epilogue: atomics ----
    {
        float* wx = ws + WS_WX + (size_t)b * CCH * KK;
#pragma unroll
        for (int p = 0; p < 4; ++p)
#pragma unroll
            for (int k = 0; k < 4; ++k) {
                atomicAdd(&wx[(cg * 8 + 2 * p) * KK + kq * 4 + k], acc2[p][k][0]);
                atomicAdd(&wx[(cg * 8 + 2 * p + 1) * KK + kq * 4 + k], acc2[p][k][1]);
            }
    }
    if (cpart == 0) {
#pragma unroll
        for (int j = 0; j < 8; ++j) wsp[w * 32 + kg + 4 * j] = wsacc[j];
    }
    __syncthreads();
    if (t < 32) {
        float s = 0.f;
#pragma unroll
        for (int p = 0; p < 8; ++p) s += wsp[p * 32 + t];
        atomicAdd(&ws[WS_WSUM + b * KK + t], s);
    }
}

// ---------------------------------------------------------------------------
// Kernel B1: enc -> BN -> ReLU -> sum_k  => encv[b][c]
// ---------------------------------------------------------------------------
__global__ __launch_bounds__(256) void encv_kernel(
    float* __restrict__ ws, const float* __restrict__ cw,
    const float* __restrict__ gamma, const float* __restrict__ beta,
    const float* __restrict__ mean, const float* __restrict__ var)
{
    __shared__ float wsum_s[KK];
    const int b = blockIdx.x;
    const int t = threadIdx.x;
    if (t < KK) wsum_s[t] = ws[WS_WSUM + b * KK + t];
    __syncthreads();
    for (int c = t; c < CCH; c += 256) {
        const float g  = gamma[c] * rsqrtf(var[c] + BN_EPS);
        const float mu = mean[c];
        const float be = beta[c];
        const float* wxr = ws + WS_WX + (size_t)(b * CCH + c) * KK;
        const float* cwr = cw + c * KK;
        float s = 0.f;
#pragma unroll
        for (int k4 = 0; k4 < KK; k4 += 4) {
            const float4 wv = *reinterpret_cast<const float4*>(wxr + k4);
            const float4 cv = *reinterpret_cast<const float4*>(cwr + k4);
            const float4 sv = *reinterpret_cast<const float4*>(&wsum_s[k4]);
            s += fmaxf((wv.x - cv.x * sv.x - mu) * g + be, 0.f);
            s += fmaxf((wv.y - cv.y * sv.y - mu) * g + be, 0.f);
            s += fmaxf((wv.z - cv.z * sv.z - mu) * g + be, 0.f);
            s += fmaxf((wv.w - cv.w * sv.w - mu) * g + be, 0.f);
        }
        ws[WS_ENC + b * CCH + c] = s;
    }
}

// ---------------------------------------------------------------------------
// Kernel B2: attn = sigmoid(encv @ w_enc + b_enc) ; se = sigmoid(encv @ w_se + b_se)
// ---------------------------------------------------------------------------
__global__ __launch_bounds__(256) void attn_se_kernel(
    float* __restrict__ ws, const float* __restrict__ w_enc,
    const float* __restrict__ b_enc, const float* __restrict__ w_se,
    const float* __restrict__ b_se, float* __restrict__ out)
{
    __shared__ float ev[CCH];
    __shared__ float red[4][64];
    const int b   = blockIdx.y;
    const int cgb = blockIdx.x;
    const int t   = threadIdx.x;
    ev[t]       = ws[WS_ENC + b * CCH + t];
    ev[t + 256] = ws[WS_ENC + b * CCH + 256 + t];
    __syncthreads();
    if (cgb < 8) {
        const int c2 = cgb * 64 + (t & 63);
        const int p  = t >> 6;
        float a = 0.f;
#pragma unroll 4
        for (int i = 0; i < 128; ++i) {
            const int c = p * 128 + i;
            a += ev[c] * w_enc[c * CCH + c2];
        }
        red[p][t & 63] = a;
        __syncthreads();
        if (t < 64) {
            const float v = red[0][t] + red[1][t] + red[2][t] + red[3][t]
                          + b_enc[cgb * 64 + t];
            ws[WS_ATTN + b * CCH + cgb * 64 + t] = 1.f / (1.f + __expf(-v));
        }
    } else if (t < 8 * CLS) {
        const int j = t >> 3, p = t & 7;
        float a = 0.f;
        for (int c = p; c < CCH; c += 8) a += ev[c] * w_se[c * CLS + j];
        a += __shfl_xor(a, 1);
        a += __shfl_xor(a, 2);
        a += __shfl_xor(a, 4);
        if (p == 0)
            out[(size_t)BB * NN * CCH + b * CLS + j] =
                1.f / (1.f + __expf(-(a + b_se[j])));
    }
}

// ---------------------------------------------------------------------------
// Kernel C: featuremaps = attn[b,c] * x
// ---------------------------------------------------------------------------
__global__ __launch_bounds__(256) void scale_out(
    const float* __restrict__ x, const float* __restrict__ ws,
    float* __restrict__ out)
{
    const int gid = blockIdx.x * 256 + threadIdx.x;
    const int c4  = (gid & 127) << 2;
#pragma unroll
    for (int b = 0; b < BB; ++b) {
        const size_t f = ((size_t)b << 19) + (size_t)gid;
        const float4 xv = *reinterpret_cast<const float4*>(x + 4 * f);
        const float4 av = *reinterpret_cast<const float4*>(ws + WS_ATTN + b * CCH + c4);
        float4 o;
        o.x = xv.x * av.x; o.y = xv.y * av.y; o.z = xv.z * av.z; o.w = xv.w * av.w;
        *reinterpret_cast<float4*>(out + 4 * f) = o;
    }
}

// ---------------------------------------------------------------------------
extern "C" void kernel_launch(void* const* d_in, const int* in_sizes, int n_in,
                              void* d_out, int out_size, void* d_ws, size_t ws_size,
                              hipStream_t stream)
{
    const float* x     = (const float*)d_in[0];
    const float* cw    = (const float*)d_in[1];
    const float* sf    = (const float*)d_in[2];
    const float* gamma = (const float*)d_in[3];
    const float* beta  = (const float*)d_in[4];
    const float* mean  = (const float*)d_in[5];
    const float* var   = (const float*)d_in[6];
    const float* w_enc = (const float*)d_in[7];
    const float* b_enc = (const float*)d_in[8];
    const float* w_se  = (const float*)d_in[9];
    const float* b_se  = (const float*)d_in[10];
    float* out = (float*)d_out;
    float* ws  = (float*)d_ws;

    hipMemsetAsync(d_ws, 0, (size_t)(WS_WSUM + BB * KK) * sizeof(float), stream);

    enc_partial<<<dim3(NBLK, BB), TPB, SM_BYTES, stream>>>(x, cw, sf, ws);
    encv_kernel<<<BB, 256, 0, stream>>>(ws, cw, gamma, beta, mean, var);
    attn_se_kernel<<<dim3(9, BB), 256, 0, stream>>>(ws, w_enc, b_enc, w_se, b_se, out);
    scale_out<<<2048, 256, 0, stream>>>(x, ws, out);
}

// Round 5
// 140.853 us; speedup vs baseline: 1.6874x; 1.6874x over previous
//
#include <hip/hip_runtime.h>

#define BB 8
#define NN 4096
#define CCH 512
#define KK 32
#define CLS 21
#define BN_EPS 1e-3f

#define TPB 512
#define CHUNK 64
#define NBLK (NN / CHUNK)   // 64 -> grid 512 blocks = 2/CU

typedef _Float16 f16;
typedef _Float16 half2v __attribute__((ext_vector_type(2)));
typedef _Float16 half4v __attribute__((ext_vector_type(4)));
typedef _Float16 half8v __attribute__((ext_vector_type(8)));
typedef float float2v __attribute__((ext_vector_type(2)));

// xn pitch in f16 units (1056 B, 16B-aligned)
#define XPH 528
#define WPH 40

// LDS carve (bytes)
#define SMB_CWL 0
#define SMB_XN  32768
#define SMB_WT  (SMB_XN + 32 * XPH * 2)      // 66560
#define SMB_F32 (SMB_WT + 32 * WPH * 2)      // 69120
#define SM_BYTES (SMB_F32 + (64 + 256 + 32 + 32) * 4)

// ---- PARTIAL-path ws layout (floats): no atomics, no memset ----
#define WS_P    0                                  // [NBLK][BB][CCH][KK]
#define WS_WSP  (NBLK * BB * CCH * KK)             // 8388608  [NBLK][BB][KK]
#define WS_ENC  (WS_WSP + NBLK * BB * KK)          // 8404992  [BB][CCH]
#define WS_ATTN (WS_ENC + BB * CCH)                // 8409088  [BB][CCH]
#define WS_END  (WS_ATTN + BB * CCH)               // 8413184 floats

// ---- ATOMIC-fallback ws layout (floats) ----
#define WA_WX   0
#define WA_WSUM (BB * CCH * KK)                    // 131072
#define WA_ENC  (WA_WSUM + BB * KK)                // 131328
#define WA_ATTN (WA_ENC + BB * CCH)                // 135424
#define WA_END  (WA_ATTN + BB * CCH)

template <int CTRL>
__device__ __forceinline__ float dpp_add(float v) {
    int r = __builtin_amdgcn_update_dpp(0, __builtin_bit_cast(int, v),
                                        CTRL, 0xF, 0xF, true);
    return v + __builtin_bit_cast(float, r);
}
__device__ __forceinline__ float rowsum16(float v) {
    v = dpp_add<0x128>(v);
    v = dpp_add<0x124>(v);
    v = dpp_add<0x122>(v);
    v = dpp_add<0x121>(v);
    return v;
}

__device__ __forceinline__ float dot8f(half8v a, half8v b, float c) {
#if __has_builtin(__builtin_amdgcn_fdot2)
    half2v a0 = {a[0], a[1]}, b0 = {b[0], b[1]};
    half2v a1 = {a[2], a[3]}, b1 = {b[2], b[3]};
    half2v a2 = {a[4], a[5]}, b2 = {b[4], b[5]};
    half2v a3 = {a[6], a[7]}, b3 = {b[6], b[7]};
    c = __builtin_amdgcn_fdot2(a0, b0, c, false);
    c = __builtin_amdgcn_fdot2(a1, b1, c, false);
    c = __builtin_amdgcn_fdot2(a2, b2, c, false);
    c = __builtin_amdgcn_fdot2(a3, b3, c, false);
    return c;
#else
#pragma unroll
    for (int i = 0; i < 8; ++i) c += (float)a[i] * (float)b[i];
    return c;
#endif
}

// ---------------------------------------------------------------------------
// Kernel A: fused cross -> softmax -> wx partials. 512 thr, 2 blocks/CU.
// PARTIAL=1: stream per-block partial tiles to ws (no atomics).
// PARTIAL=0: legacy atomicAdd path (small-ws fallback).
// ---------------------------------------------------------------------------
template <int PARTIAL>
__global__ __launch_bounds__(TPB, 2) void enc_partial(
    const float* __restrict__ x, const float* __restrict__ cw,
    const float* __restrict__ sf, float* __restrict__ ws)
{
    extern __shared__ char smraw[];
    f16*   cwL  = (f16*)(smraw + SMB_CWL);
    f16*   xn   = (f16*)(smraw + SMB_XN);
    f16*   wt   = (f16*)(smraw + SMB_WT);
    float* xsqp = (float*)(smraw + SMB_F32);          // [8 waves][8 rows]
    float* wsp  = xsqp + 64;                          // [8][32] scratch
    float* cwsqL = wsp + 256;                         // [32]
    float* nsfL  = cwsqL + 32;                        // [32]

    const int t = threadIdx.x;
    const int b = blockIdx.y;
    const int w = t >> 6;
    const int l = t & 63;
    const int cpart = t & 15;
    const int kg    = (t >> 4) & 3;

    // ---- build cwL ----
    {
        for (int pi = 0; pi < 4; ++pi) {
            const int pair = w * 4 + pi;        // 0..31
            const int s = pair >> 3, j = pair & 7;
            const int k = ((l >> 4) & 3) + 4 * j;
            half8v v;
#pragma unroll
            for (int e = 0; e < 8; ++e) {
                const int c = (l & 15) * 8 + s * 128 + e;
                v[e] = (f16)cw[c * KK + k];
            }
            *reinterpret_cast<half8v*>(cwL + ((size_t)pair * 64 + l) * 8) = v;
        }
    }
    // ---- cwsq partials ----
    if (t < 256) {
        const int k = t & 31, part = t >> 5;
        float s = 0.f;
        for (int c = part * 64; c < part * 64 + 64; ++c) {
            const float v = cw[c * KK + k];
            s += v * v;
        }
        wsp[part * 32 + k] = s;
    }
    __syncthreads();
    if (t < 32) {
        float s = 0.f;
#pragma unroll
        for (int p = 0; p < 8; ++p) s += wsp[p * 32 + t];
        cwsqL[t] = s;
        nsfL[t]  = -sf[t];
    }
    __syncthreads();

    const int kq = t & 7;
    const int cg = t >> 3;    // 0..63, c-oct = cg*8

    float2v acc2[4][4];
#pragma unroll
    for (int p = 0; p < 4; ++p)
#pragma unroll
        for (int k = 0; k < 4; ++k) acc2[p][k] = (float2v){0.f, 0.f};
    float wsacc[8] = {0.f, 0.f, 0.f, 0.f, 0.f, 0.f, 0.f, 0.f};

    const int n0base = blockIdx.x * CHUNK;
    for (int tile = 0; tile < CHUNK / 32; ++tile) {
        const int n0 = n0base + tile * 32;

        // ---- stage 32x512 fp32 -> f16 LDS; exact fp32 x_sq on the fly ----
        {
            float sqp[8];
#pragma unroll
            for (int i = 0; i < 8; ++i) {
                const int f  = i * TPB + t;
                const int rr = f >> 7;
                const int c4 = (f & 127) << 2;
                const float4 v = *reinterpret_cast<const float4*>(
                    x + (size_t)(b * NN + n0 + rr) * CCH + c4);
                sqp[i] = v.x * v.x + v.y * v.y + v.z * v.z + v.w * v.w;
                half4v h = {(f16)v.x, (f16)v.y, (f16)v.z, (f16)v.w};
                *reinterpret_cast<half4v*>(xn + rr * XPH + c4) = h;
            }
#pragma unroll
            for (int i = 0; i < 8; ++i) {
                float v = sqp[i];
                v += __shfl_xor(v, 1);  v += __shfl_xor(v, 2);
                v += __shfl_xor(v, 4);  v += __shfl_xor(v, 8);
                v += __shfl_xor(v, 16); v += __shfl_xor(v, 32);
                if (l == 0) xsqp[w * 8 + i] = v;
            }
        }
        __syncthreads();

        // ---- B2: cross via fdot2; wave w handles rows 4w..4w+3 ----
        float cr[4][8];
#pragma unroll
        for (int q = 0; q < 4; ++q)
#pragma unroll
            for (int j = 0; j < 8; ++j) cr[q][j] = 0.f;

        for (int s = 0; s < 4; ++s) {
            half8v xv[4];
#pragma unroll
            for (int q = 0; q < 4; ++q)
                xv[q] = *reinterpret_cast<const half8v*>(
                    xn + (w * 4 + q) * XPH + s * 128 + cpart * 8);
#pragma unroll
            for (int j = 0; j < 8; ++j) {
                const half8v cv = *reinterpret_cast<const half8v*>(
                    cwL + ((size_t)(s * 8 + j) * 64 + l) * 8);
#pragma unroll
                for (int q = 0; q < 4; ++q) cr[q][j] = dot8f(xv[q], cv, cr[q][j]);
            }
        }
#pragma unroll
        for (int q = 0; q < 4; ++q)
#pragma unroll
            for (int j = 0; j < 8; ++j) cr[q][j] = rowsum16(cr[q][j]);

        // ---- softmax over 32 k ----
        {
            float nsf[8], cq[8];
#pragma unroll
            for (int j = 0; j < 8; ++j) {
                nsf[j] = nsfL[kg + 4 * j];
                cq[j]  = cwsqL[kg + 4 * j];
            }
#pragma unroll
            for (int q = 0; q < 4; ++q) {
                const int r = w * 4 + q;
                const float xs = xsqp[(2 * (r & 3)) * 8 + (r >> 2)]
                               + xsqp[(2 * (r & 3) + 1) * 8 + (r >> 2)];
                float lg[8];
#pragma unroll
                for (int j = 0; j < 8; ++j)
                    lg[j] = (xs - 2.f * cr[q][j] + cq[j]) * nsf[j];
                float m = lg[0];
#pragma unroll
                for (int j = 1; j < 8; ++j) m = fmaxf(m, lg[j]);
                m = fmaxf(m, __shfl_xor(m, 16));
                m = fmaxf(m, __shfl_xor(m, 32));
                float e[8], ssum = 0.f;
#pragma unroll
                for (int j = 0; j < 8; ++j) { e[j] = __expf(lg[j] - m); ssum += e[j]; }
                ssum += __shfl_xor(ssum, 16);
                ssum += __shfl_xor(ssum, 32);
                const float inv = 1.f / ssum;
                if (cpart == 0) {
#pragma unroll
                    for (int j = 0; j < 8; ++j) {
                        const float wv = e[j] * inv;
                        wsacc[j] += wv;
                        wt[r * WPH + kg + 4 * j] = (f16)wv;
                    }
                }
            }
        }
        __syncthreads();   // wt ready

        // ---- C: wx[c][k] += w[n][k]*x[n][c], 8c x 4k per thread, all 32 rows ----
#pragma unroll 4
        for (int rr = 0; rr < 32; ++rr) {
            const half8v xv = *reinterpret_cast<const half8v*>(xn + rr * XPH + cg * 8);
            const half4v wv = *reinterpret_cast<const half4v*>(wt + rr * WPH + kq * 4);
            const float wk0 = (float)wv[0], wk1 = (float)wv[1];
            const float wk2 = (float)wv[2], wk3 = (float)wv[3];
#pragma unroll
            for (int p = 0; p < 4; ++p) {
                const float2v xf = {(float)xv[2 * p], (float)xv[2 * p + 1]};
                acc2[p][0] += xf * (float2v){wk0, wk0};
                acc2[p][1] += xf * (float2v){wk1, wk1};
                acc2[p][2] += xf * (float2v){wk2, wk2};
                acc2[p][3] += xf * (float2v){wk3, wk3};
            }
        }
        __syncthreads();   // protect xn/wt before next tile
    }

    // ---- epilogue ----
    if (PARTIAL) {
        // stream full partial tile: p[chunk][b][c][k], plain dwordx4 stores
        float* pp = ws + WS_P + (((size_t)blockIdx.x * BB + b) * CCH) * KK;
#pragma unroll
        for (int q = 0; q < 8; ++q) {
            const float4 v = make_float4(acc2[q >> 1][0][q & 1], acc2[q >> 1][1][q & 1],
                                         acc2[q >> 1][2][q & 1], acc2[q >> 1][3][q & 1]);
            *reinterpret_cast<float4*>(pp + (size_t)(cg * 8 + q) * KK + kq * 4) = v;
        }
    } else {
        float* wx = ws + WA_WX + (size_t)b * CCH * KK;
#pragma unroll
        for (int p = 0; p < 4; ++p)
#pragma unroll
            for (int k = 0; k < 4; ++k) {
                atomicAdd(&wx[(cg * 8 + 2 * p) * KK + kq * 4 + k], acc2[p][k][0]);
                atomicAdd(&wx[(cg * 8 + 2 * p + 1) * KK + kq * 4 + k], acc2[p][k][1]);
            }
    }
    if (cpart == 0) {
#pragma unroll
        for (int j = 0; j < 8; ++j) wsp[w * 32 + kg + 4 * j] = wsacc[j];
    }
    __syncthreads();
    if (t < 32) {
        float s = 0.f;
#pragma unroll
        for (int p = 0; p < 8; ++p) s += wsp[p * 32 + t];
        if (PARTIAL)
            ws[WS_WSP + ((size_t)blockIdx.x * BB + b) * KK + t] = s;
        else
            atomicAdd(&ws[WA_WSUM + b * KK + t], s);
    }
}

// ---------------------------------------------------------------------------
// Kernel R (PARTIAL path): reduce partials + enc -> BN -> ReLU -> sum_k => encv
// grid (16 cslices, 8 b), 256 thr; thread = (c_local = t>>3, kq = t&7)
// ---------------------------------------------------------------------------
__global__ __launch_bounds__(256) void reduce_encv(
    float* __restrict__ ws, const float* __restrict__ cw,
    const float* __restrict__ gamma, const float* __restrict__ beta,
    const float* __restrict__ mean, const float* __restrict__ var)
{
    __shared__ float wsum_s[KK];
    const int b  = blockIdx.y;
    const int cs = blockIdx.x;
    const int t  = threadIdx.x;

    if (t < KK) {
        float s = 0.f;
        for (int ch = 0; ch < NBLK; ++ch)
            s += ws[WS_WSP + ((size_t)ch * BB + b) * KK + t];
        wsum_s[t] = s;
    }
    __syncthreads();

    const int cl = t >> 3;
    const int c  = cs * 32 + cl;
    const int kq = t & 7;

    float4 a = make_float4(0.f, 0.f, 0.f, 0.f);
    for (int ch = 0; ch < NBLK; ++ch) {
        const float4 v = *reinterpret_cast<const float4*>(
            ws + WS_P + (((size_t)ch * BB + b) * CCH + c) * KK + kq * 4);
        a.x += v.x; a.y += v.y; a.z += v.z; a.w += v.w;
    }
    const float g  = gamma[c] * rsqrtf(var[c] + BN_EPS);
    const float mu = mean[c];
    const float be = beta[c];
    const float4 cv = *reinterpret_cast<const float4*>(cw + c * KK + kq * 4);
    const float4 sv = *reinterpret_cast<const float4*>(&wsum_s[kq * 4]);
    float s = 0.f;
    s += fmaxf((a.x - cv.x * sv.x - mu) * g + be, 0.f);
    s += fmaxf((a.y - cv.y * sv.y - mu) * g + be, 0.f);
    s += fmaxf((a.z - cv.z * sv.z - mu) * g + be, 0.f);
    s += fmaxf((a.w - cv.w * sv.w - mu) * g + be, 0.f);
    s += __shfl_xor(s, 1);
    s += __shfl_xor(s, 2);
    s += __shfl_xor(s, 4);
    if (kq == 0) ws[WS_ENC + (size_t)b * CCH + c] = s;
}

// ---------------------------------------------------------------------------
// Kernel B1 (fallback): enc -> BN -> ReLU -> sum_k => encv (atomic layout)
// ---------------------------------------------------------------------------
__global__ __launch_bounds__(256) void encv_kernel(
    float* __restrict__ ws, const float* __restrict__ cw,
    const float* __restrict__ gamma, const float* __restrict__ beta,
    const float* __restrict__ mean, const float* __restrict__ var)
{
    __shared__ float wsum_s[KK];
    const int b = blockIdx.x;
    const int t = threadIdx.x;
    if (t < KK) wsum_s[t] = ws[WA_WSUM + b * KK + t];
    __syncthreads();
    for (int c = t; c < CCH; c += 256) {
        const float g  = gamma[c] * rsqrtf(var[c] + BN_EPS);
        const float mu = mean[c];
        const float be = beta[c];
        const float* wxr = ws + WA_WX + (size_t)(b * CCH + c) * KK;
        const float* cwr = cw + c * KK;
        float s = 0.f;
#pragma unroll
        for (int k4 = 0; k4 < KK; k4 += 4) {
            const float4 wv = *reinterpret_cast<const float4*>(wxr + k4);
            const float4 cv = *reinterpret_cast<const float4*>(cwr + k4);
            const float4 sv = *reinterpret_cast<const float4*>(&wsum_s[k4]);
            s += fmaxf((wv.x - cv.x * sv.x - mu) * g + be, 0.f);
            s += fmaxf((wv.y - cv.y * sv.y - mu) * g + be, 0.f);
            s += fmaxf((wv.z - cv.z * sv.z - mu) * g + be, 0.f);
            s += fmaxf((wv.w - cv.w * sv.w - mu) * g + be, 0.f);
        }
        ws[WA_ENC + b * CCH + c] = s;
    }
}

// ---------------------------------------------------------------------------
// Kernel B2: attn = sigmoid(encv @ w_enc + b_enc) ; se = sigmoid(encv @ w_se + b_se)
// ---------------------------------------------------------------------------
__global__ __launch_bounds__(256) void attn_se_kernel(
    const float* __restrict__ enc, float* __restrict__ attn,
    const float* __restrict__ w_enc, const float* __restrict__ b_enc,
    const float* __restrict__ w_se, const float* __restrict__ b_se,
    float* __restrict__ out)
{
    __shared__ float ev[CCH];
    __shared__ float red[4][64];
    const int b   = blockIdx.y;
    const int cgb = blockIdx.x;
    const int t   = threadIdx.x;
    ev[t]       = enc[(size_t)b * CCH + t];
    ev[t + 256] = enc[(size_t)b * CCH + 256 + t];
    __syncthreads();
    if (cgb < 8) {
        const int c2 = cgb * 64 + (t & 63);
        const int p  = t >> 6;
        float a = 0.f;
#pragma unroll 4
        for (int i = 0; i < 128; ++i) {
            const int c = p * 128 + i;
            a += ev[c] * w_enc[c * CCH + c2];
        }
        red[p][t & 63] = a;
        __syncthreads();
        if (t < 64) {
            const float v = red[0][t] + red[1][t] + red[2][t] + red[3][t]
                          + b_enc[cgb * 64 + t];
            attn[(size_t)b * CCH + cgb * 64 + t] = 1.f / (1.f + __expf(-v));
        }
    } else if (t < 8 * CLS) {
        const int j = t >> 3, p = t & 7;
        float a = 0.f;
        for (int c = p; c < CCH; c += 8) a += ev[c] * w_se[c * CLS + j];
        a += __shfl_xor(a, 1);
        a += __shfl_xor(a, 2);
        a += __shfl_xor(a, 4);
        if (p == 0)
            out[(size_t)BB * NN * CCH + b * CLS + j] =
                1.f / (1.f + __expf(-(a + b_se[j])));
    }
}

// ---------------------------------------------------------------------------
// Kernel C: featuremaps = attn[b,c] * x
// ---------------------------------------------------------------------------
__global__ __launch_bounds__(256) void scale_out(
    const float* __restrict__ x, const float* __restrict__ attn,
    float* __restrict__ out)
{
    const int gid = blockIdx.x * 256 + threadIdx.x;
    const int c4  = (gid & 127) << 2;
#pragma unroll
    for (int b = 0; b < BB; ++b) {
        const size_t f = ((size_t)b << 19) + (size_t)gid;
        const float4 xv = *reinterpret_cast<const float4*>(x + 4 * f);
        const float4 av = *reinterpret_cast<const float4*>(attn + (size_t)b * CCH + c4);
        float4 o;
        o.x = xv.x * av.x; o.y = xv.y * av.y; o.z = xv.z * av.z; o.w = xv.w * av.w;
        *reinterpret_cast<float4*>(out + 4 * f) = o;
    }
}

// ---------------------------------------------------------------------------
extern "C" void kernel_launch(void* const* d_in, const int* in_sizes, int n_in,
                              void* d_out, int out_size, void* d_ws, size_t ws_size,
                              hipStream_t stream)
{
    const float* x     = (const float*)d_in[0];
    const float* cw    = (const float*)d_in[1];
    const float* sf    = (const float*)d_in[2];
    const float* gamma = (const float*)d_in[3];
    const float* beta  = (const float*)d_in[4];
    const float* mean  = (const float*)d_in[5];
    const float* var   = (const float*)d_in[6];
    const float* w_enc = (const float*)d_in[7];
    const float* b_enc = (const float*)d_in[8];
    const float* w_se  = (const float*)d_in[9];
    const float* b_se  = (const float*)d_in[10];
    float* out = (float*)d_out;
    float* ws  = (float*)d_ws;

    if (ws_size >= (size_t)WS_END * sizeof(float)) {
        // partial-tile path: no atomics, no memset
        enc_partial<1><<<dim3(NBLK, BB), TPB, SM_BYTES, stream>>>(x, cw, sf, ws);
        reduce_encv<<<dim3(16, BB), 256, 0, stream>>>(ws, cw, gamma, beta, mean, var);
        attn_se_kernel<<<dim3(9, BB), 256, 0, stream>>>(
            ws + WS_ENC, ws + WS_ATTN, w_enc, b_enc, w_se, b_se, out);
        scale_out<<<2048, 256, 0, stream>>>(x, ws + WS_ATTN, out);
    } else {
        hipMemsetAsync(d_ws, 0, (size_t)(WA_WSUM + BB * KK) * sizeof(float), stream);
        enc_partial<0><<<dim3(NBLK, BB), TPB, SM_BYTES, stream>>>(x, cw, sf, ws);
        encv_kernel<<<BB, 256, 0, stream>>>(ws, cw, gamma, beta, mean, var);
        attn_se_kernel<<<dim3(9, BB), 256, 0, stream>>>(
            ws + WA_ENC, ws + WA_ATTN, w_enc, b_enc, w_se, b_se, out);
        scale_out<<<2048, 256, 0, stream>>>(x, ws + WA_ATTN, out);
    }
}

// Round 6
// 94.098 us; speedup vs baseline: 2.5258x; 1.4969x over previous
//
#include <hip/hip_runtime.h>

#define BB 8
#define NN 4096
#define CCH 512
#define KK 32
#define CLS 21
#define BN_EPS 1e-3f

#define TPB 512
#define CHUNK 64
#define NBLK (NN / CHUNK)   // 64 -> grid (64,8) = 512 blocks = 2/CU

typedef _Float16 f16;
typedef _Float16 f16x4 __attribute__((ext_vector_type(4)));
typedef _Float16 f16x8 __attribute__((ext_vector_type(8)));
typedef float f32x4 __attribute__((ext_vector_type(4)));

#define NP 36    // xnT / wtT row pitch in f16 (rows 8B-aligned, <=2-way-extra banks)

// LDS carve (bytes)
#define LB_XNT  0                         // f16[512][NP]      36864
#define LB_CWB  36864                     // f16[2][16][64][8] 32768
#define LB_WTT  69632                     // f16[32][NP]        2304
#define LB_RED  71936                     // f32[6][64][4]      6144
#define LB_XSQ  78080                     // f32[2ch][2m][16]    256
#define LB_CSQ  78336                     // f32[32]             128
#define LB_NSF  78464                     // f32[32]             128
#define LB_WSQ  78592                     // f32[2w][2kt][16]    256
#define LB_TOT  78848                     // x2 blocks = 157696 <= 160K

// ws layout (floats) — identical to r5 partial path
#define WS_P    0                                  // [NBLK][BB][CCH][KK]
#define WS_WSP  (NBLK * BB * CCH * KK)             // 8388608
#define WS_ENC  (WS_WSP + NBLK * BB * KK)          // 8404992
#define WS_ATTN (WS_ENC + BB * CCH)                // 8409088
#define WS_END  (WS_ATTN + BB * CCH)

template <int CTRL>
__device__ __forceinline__ float dpp_add(float v) {
    int r = __builtin_amdgcn_update_dpp(0, __builtin_bit_cast(int, v),
                                        CTRL, 0xF, 0xF, true);
    return v + __builtin_bit_cast(float, r);
}
template <int CTRL>
__device__ __forceinline__ float dpp_max(float v) {
    int r = __builtin_amdgcn_update_dpp(0, __builtin_bit_cast(int, v),
                                        CTRL, 0xF, 0xF, true);
    return fmaxf(v, __builtin_bit_cast(float, r));
}
__device__ __forceinline__ float rowsum16(float v) {
    v = dpp_add<0x128>(v); v = dpp_add<0x124>(v);
    v = dpp_add<0x122>(v); v = dpp_add<0x121>(v);
    return v;
}
__device__ __forceinline__ float rowmax16(float v) {
    v = dpp_max<0x128>(v); v = dpp_max<0x124>(v);
    v = dpp_max<0x122>(v); v = dpp_max<0x121>(v);
    return v;
}

// ---------------------------------------------------------------------------
// Kernel A (MFMA): fused cross -> softmax -> wx partials.
// Wave roles in cross: m=w&1 (16-row half), kt=(w>>1)&1 (16-k tile), ch=w>>2
// (256-c half). A-frag: lane l holds x[n=16m+(l&15)][c=cstep*32+(l>>4)*8+i].
// B-frag (cwB pre-layout): lane l holds cw[c=cstep*32+(l>>4)*8+i][k=(l&15)+16kt].
// D-frag: row n-sub=(l>>4)*4+r, col k=(l&15)  [guide m89].
// wx: A=wtT[k][n] (M=k), B=xnT[c][n] (N=c), one K=32 step per tile.
// ---------------------------------------------------------------------------
__global__ __launch_bounds__(TPB, 2) void enc_mfma(
    const float* __restrict__ x, const float* __restrict__ cw,
    const float* __restrict__ sf, float* __restrict__ ws)
{
    extern __shared__ char sm[];
    f16*   xnT  = (f16*)(sm + LB_XNT);
    f16*   cwB  = (f16*)(sm + LB_CWB);
    f16*   wtT  = (f16*)(sm + LB_WTT);
    float* red  = (float*)(sm + LB_RED);
    float* xsq  = (float*)(sm + LB_XSQ);
    float* csqL = (float*)(sm + LB_CSQ);
    float* nsfL = (float*)(sm + LB_NSF);
    float* wsq  = (float*)(sm + LB_WSQ);

    const int t = threadIdx.x;
    const int b = blockIdx.y;
    const int w = t >> 6;
    const int l = t & 63;
    const int a = l & 15;
    const int g = l >> 4;

    // ---- stage cwB in B-fragment layout (once per block) ----
    for (int si = 0; si < 4; ++si) {
        const int s     = si * 512 + t;        // 0..2047
        const int lane  = s & 63;
        const int cstep = (s >> 6) & 15;
        const int kt    = s >> 10;
        const int k     = (lane & 15) + 16 * kt;
        const int c0    = cstep * 32 + (lane >> 4) * 8;
        f16x8 v;
#pragma unroll
        for (int i = 0; i < 8; ++i) v[i] = (f16)cw[(c0 + i) * KK + k];
        *reinterpret_cast<f16x8*>(cwB + ((size_t)(kt * 16 + cstep) * 64 + lane) * 8) = v;
    }
    // ---- cwsq partials (red used as scratch) ----
    if (t < 256) {
        const int k = t & 31, part = t >> 5;
        float sacc = 0.f;
        for (int c = part * 64; c < part * 64 + 64; ++c) {
            const float v = cw[c * KK + k];
            sacc += v * v;
        }
        red[part * 32 + k] = sacc;
    }
    __syncthreads();
    if (t < 32) {
        float sacc = 0.f;
#pragma unroll
        for (int p = 0; p < 8; ++p) sacc += red[p * 32 + t];
        csqL[t] = sacc;
        nsfL[t] = -sf[t];
    }
    __syncthreads();

    const int m_  = w & 1;
    const int kt_ = (w >> 1) & 1;
    const int ch_ = w >> 2;

    f32x4 acc[4][2];
#pragma unroll
    for (int ct = 0; ct < 4; ++ct)
#pragma unroll
        for (int kt = 0; kt < 2; ++kt) acc[ct][kt] = (f32x4){0.f, 0.f, 0.f, 0.f};
    float wsacc0 = 0.f, wsacc1 = 0.f;

    for (int tile = 0; tile < 2; ++tile) {
        const int n0 = blockIdx.x * CHUNK + tile * 32;

        // ---- stage xnT: column-order loads (lane=c pair), transposed writes ----
#pragma unroll
        for (int i = 0; i < 16; ++i) {
            const int idx = i * 512 + t;      // 0..8191 = 32 rows x 256 c-pairs
            const int row = idx >> 8;
            const int c   = (idx & 255) * 2;
            const float2 v = *reinterpret_cast<const float2*>(
                x + (size_t)(b * NN + n0 + row) * CCH + c);
            xnT[(c    ) * NP + row] = (f16)v.x;
            xnT[(c + 1) * NP + row] = (f16)v.y;
        }

        // ---- cross MFMA: A-frags from global, B-frags from cwB ----
        f32x4 d = {0.f, 0.f, 0.f, 0.f};
        float sq = 0.f;
        const float* xrow = x + (size_t)(b * NN + n0 + 16 * m_ + a) * CCH;
#pragma unroll
        for (int cs = 0; cs < 8; ++cs) {
            const int cstep = ch_ * 8 + cs;
            const int c0 = cstep * 32 + g * 8;
            const float4 u0 = *reinterpret_cast<const float4*>(xrow + c0);
            const float4 u1 = *reinterpret_cast<const float4*>(xrow + c0 + 4);
            if (kt_ == 0)
                sq += u0.x*u0.x + u0.y*u0.y + u0.z*u0.z + u0.w*u0.w
                    + u1.x*u1.x + u1.y*u1.y + u1.z*u1.z + u1.w*u1.w;
            const f16x8 af = {(f16)u0.x, (f16)u0.y, (f16)u0.z, (f16)u0.w,
                              (f16)u1.x, (f16)u1.y, (f16)u1.z, (f16)u1.w};
            const f16x8 bf = *reinterpret_cast<const f16x8*>(
                cwB + ((size_t)(kt_ * 16 + cstep) * 64 + l) * 8);
            d = __builtin_amdgcn_mfma_f32_16x16x32_f16(af, bf, d, 0, 0, 0);
        }
        if (kt_ == 0) {
            sq += __shfl_xor(sq, 16);
            sq += __shfl_xor(sq, 32);
            if (l < 16) xsq[(ch_ * 2 + m_) * 16 + l] = sq;   // rows 0..15 of m-half
        }
        if (w >= 2)
            *reinterpret_cast<f32x4*>(red + ((w - 2) * 64 + l) * 4) = d;
        __syncthreads();   // B1: xnT, xsq, red ready

        // ---- softmax (waves 0,1; m = w) ----
        if (w < 2) {
            const f32x4 r0 = *reinterpret_cast<const f32x4*>(red + ((w + 2) * 64 + l) * 4); // (m,kt0,ch1)
            const f32x4 r1 = *reinterpret_cast<const f32x4*>(red + ((w    ) * 64 + l) * 4); // (m,kt1,ch0)
            const f32x4 r2 = *reinterpret_cast<const f32x4*>(red + ((w + 4) * 64 + l) * 4); // (m,kt1,ch1)
            const f32x4 d0 = d + r0;
            const f32x4 d1 = r1 + r2;
            const float cq0 = csqL[a],  cq1 = csqL[a + 16];
            const float sf0 = nsfL[a],  sf1 = nsfL[a + 16];
#pragma unroll
            for (int r = 0; r < 4; ++r) {
                const int row = 4 * g + r;                   // 0..15 within m-half
                const float xs = xsq[(0 * 2 + w) * 16 + row]
                               + xsq[(1 * 2 + w) * 16 + row];
                const float l0 = (xs - 2.f * d0[r] + cq0) * sf0;
                const float l1 = (xs - 2.f * d1[r] + cq1) * sf1;
                const float mx = rowmax16(fmaxf(l0, l1));
                const float e0 = __expf(l0 - mx);
                const float e1 = __expf(l1 - mx);
                const float inv = 1.f / rowsum16(e0 + e1);
                const float w0 = e0 * inv, w1 = e1 * inv;
                wsacc0 += w0; wsacc1 += w1;
                const int n = 16 * w + row;                  // row within tile
                wtT[(a     ) * NP + n] = (f16)w0;
                wtT[(a + 16) * NP + n] = (f16)w1;
            }
        }
        __syncthreads();   // B2: wtT ready

        // ---- wx MFMA: wave owns c-slice w*64, K = 32 rows in one step ----
        {
            union { f16x8 v; f16x4 h[2]; } A0, A1;
            A0.h[0] = *reinterpret_cast<const f16x4*>(wtT + (a     ) * NP + g * 8);
            A0.h[1] = *reinterpret_cast<const f16x4*>(wtT + (a     ) * NP + g * 8 + 4);
            A1.h[0] = *reinterpret_cast<const f16x4*>(wtT + (a + 16) * NP + g * 8);
            A1.h[1] = *reinterpret_cast<const f16x4*>(wtT + (a + 16) * NP + g * 8 + 4);
#pragma unroll
            for (int ct = 0; ct < 4; ++ct) {
                const int c = w * 64 + ct * 16 + a;
                union { f16x8 v; f16x4 h[2]; } B;
                B.h[0] = *reinterpret_cast<const f16x4*>(xnT + (size_t)c * NP + g * 8);
                B.h[1] = *reinterpret_cast<const f16x4*>(xnT + (size_t)c * NP + g * 8 + 4);
                acc[ct][0] = __builtin_amdgcn_mfma_f32_16x16x32_f16(A0.v, B.v, acc[ct][0], 0, 0, 0);
                acc[ct][1] = __builtin_amdgcn_mfma_f32_16x16x32_f16(A1.v, B.v, acc[ct][1], 0, 0, 0);
            }
        }
        __syncthreads();   // B3: protect xnT/wtT/red/xsq for next tile
    }

    // ---- epilogue: stream wx partials (D[k][c] frag -> pp[c*32+k] float4) ----
    {
        float* pp = ws + WS_P + ((size_t)(blockIdx.x * BB + b)) * CCH * KK;
#pragma unroll
        for (int ct = 0; ct < 4; ++ct) {
            const int c = w * 64 + ct * 16 + a;
#pragma unroll
            for (int kt = 0; kt < 2; ++kt)
                *reinterpret_cast<f32x4*>(pp + (size_t)c * KK + kt * 16 + g * 4) = acc[ct][kt];
        }
    }
    if (w < 2) {
        float s0 = wsacc0, s1 = wsacc1;
        s0 += __shfl_xor(s0, 16); s0 += __shfl_xor(s0, 32);
        s1 += __shfl_xor(s1, 16); s1 += __shfl_xor(s1, 32);
        if (l < 16) {
            wsq[(w * 2 + 0) * 16 + l] = s0;
            wsq[(w * 2 + 1) * 16 + l] = s1;
        }
    }
    __syncthreads();
    if (t < 32) {
        const int kt = t >> 4, kk_ = t & 15;
        ws[WS_WSP + ((size_t)blockIdx.x * BB + b) * KK + t] =
            wsq[(0 * 2 + kt) * 16 + kk_] + wsq[(1 * 2 + kt) * 16 + kk_];
    }
}

// ---------------------------------------------------------------------------
// Kernel R: reduce partials + enc -> BN -> ReLU -> sum_k => encv
// ---------------------------------------------------------------------------
__global__ __launch_bounds__(256) void reduce_encv(
    float* __restrict__ ws, const float* __restrict__ cw,
    const float* __restrict__ gamma, const float* __restrict__ beta,
    const float* __restrict__ mean, const float* __restrict__ var)
{
    __shared__ float wsum_s[KK];
    const int b  = blockIdx.y;
    const int cs = blockIdx.x;
    const int t  = threadIdx.x;

    if (t < KK) {
        float s = 0.f;
        for (int ch = 0; ch < NBLK; ++ch)
            s += ws[WS_WSP + ((size_t)ch * BB + b) * KK + t];
        wsum_s[t] = s;
    }
    __syncthreads();

    const int cl = t >> 3;
    const int c  = cs * 32 + cl;
    const int kq = t & 7;

    float4 aa = make_float4(0.f, 0.f, 0.f, 0.f);
    for (int ch = 0; ch < NBLK; ++ch) {
        const float4 v = *reinterpret_cast<const float4*>(
            ws + WS_P + (((size_t)ch * BB + b) * CCH + c) * KK + kq * 4);
        aa.x += v.x; aa.y += v.y; aa.z += v.z; aa.w += v.w;
    }
    const float g  = gamma[c] * rsqrtf(var[c] + BN_EPS);
    const float mu = mean[c];
    const float be = beta[c];
    const float4 cv = *reinterpret_cast<const float4*>(cw + c * KK + kq * 4);
    const float4 sv = *reinterpret_cast<const float4*>(&wsum_s[kq * 4]);
    float s = 0.f;
    s += fmaxf((aa.x - cv.x * sv.x - mu) * g + be, 0.f);
    s += fmaxf((aa.y - cv.y * sv.y - mu) * g + be, 0.f);
    s += fmaxf((aa.z - cv.z * sv.z - mu) * g + be, 0.f);
    s += fmaxf((aa.w - cv.w * sv.w - mu) * g + be, 0.f);
    s += __shfl_xor(s, 1);
    s += __shfl_xor(s, 2);
    s += __shfl_xor(s, 4);
    if (kq == 0) ws[WS_ENC + (size_t)b * CCH + c] = s;
}

// ---------------------------------------------------------------------------
// Kernel B2: attn = sigmoid(encv @ w_enc + b_enc) ; se = sigmoid(encv @ w_se + b_se)
// ---------------------------------------------------------------------------
__global__ __launch_bounds__(256) void attn_se_kernel(
    const float* __restrict__ enc, float* __restrict__ attn,
    const float* __restrict__ w_enc, const float* __restrict__ b_enc,
    const float* __restrict__ w_se, const float* __restrict__ b_se,
    float* __restrict__ out)
{
    __shared__ float ev[CCH];
    __shared__ float red[4][64];
    const int b   = blockIdx.y;
    const int cgb = blockIdx.x;
    const int t   = threadIdx.x;
    ev[t]       = enc[(size_t)b * CCH + t];
    ev[t + 256] = enc[(size_t)b * CCH + 256 + t];
    __syncthreads();
    if (cgb < 8) {
        const int c2 = cgb * 64 + (t & 63);
        const int p  = t >> 6;
        float a = 0.f;
#pragma unroll 4
        for (int i = 0; i < 128; ++i) {
            const int c = p * 128 + i;
            a += ev[c] * w_enc[c * CCH + c2];
        }
        red[p][t & 63] = a;
        __syncthreads();
        if (t < 64) {
            const float v = red[0][t] + red[1][t] + red[2][t] + red[3][t]
                          + b_enc[cgb * 64 + t];
            attn[(size_t)b * CCH + cgb * 64 + t] = 1.f / (1.f + __expf(-v));
        }
    } else if (t < 8 * CLS) {
        const int j = t >> 3, p = t & 7;
        float a = 0.f;
        for (int c = p; c < CCH; c += 8) a += ev[c] * w_se[c * CLS + j];
        a += __shfl_xor(a, 1);
        a += __shfl_xor(a, 2);
        a += __shfl_xor(a, 4);
        if (p == 0)
            out[(size_t)BB * NN * CCH + b * CLS + j] =
                1.f / (1.f + __expf(-(a + b_se[j])));
    }
}

// ---------------------------------------------------------------------------
// Kernel C: featuremaps = attn[b,c] * x
// ---------------------------------------------------------------------------
__global__ __launch_bounds__(256) void scale_out(
    const float* __restrict__ x, const float* __restrict__ attn,
    float* __restrict__ out)
{
    const int gid = blockIdx.x * 256 + threadIdx.x;
    const int c4  = (gid & 127) << 2;
#pragma unroll
    for (int b = 0; b < BB; ++b) {
        const size_t f = ((size_t)b << 19) + (size_t)gid;
        const float4 xv = *reinterpret_cast<const float4*>(x + 4 * f);
        const float4 av = *reinterpret_cast<const float4*>(attn + (size_t)b * CCH + c4);
        float4 o;
        o.x = xv.x * av.x; o.y = xv.y * av.y; o.z = xv.z * av.z; o.w = xv.w * av.w;
        *reinterpret_cast<float4*>(out + 4 * f) = o;
    }
}

// ---------------------------------------------------------------------------
extern "C" void kernel_launch(void* const* d_in, const int* in_sizes, int n_in,
                              void* d_out, int out_size, void* d_ws, size_t ws_size,
                              hipStream_t stream)
{
    const float* x     = (const float*)d_in[0];
    const float* cw    = (const float*)d_in[1];
    const float* sf    = (const float*)d_in[2];
    const float* gamma = (const float*)d_in[3];
    const float* beta  = (const float*)d_in[4];
    const float* mean  = (const float*)d_in[5];
    const float* var   = (const float*)d_in[6];
    const float* w_enc = (const float*)d_in[7];
    const float* b_enc = (const float*)d_in[8];
    const float* w_se  = (const float*)d_in[9];
    const float* b_se  = (const float*)d_in[10];
    float* out = (float*)d_out;
    float* ws  = (float*)d_ws;

    enc_mfma<<<dim3(NBLK, BB), TPB, LB_TOT, stream>>>(x, cw, sf, ws);
    reduce_encv<<<dim3(16, BB), 256, 0, stream>>>(ws, cw, gamma, beta, mean, var);
    attn_se_kernel<<<dim3(9, BB), 256, 0, stream>>>(
        ws + WS_ENC, ws + WS_ATTN, w_enc, b_enc, w_se, b_se, out);
    scale_out<<<2048, 256, 0, stream>>>(x, ws + WS_ATTN, out);
}

// Round 7
// 91.718 us; speedup vs baseline: 2.5914x; 1.0260x over previous
//
#include <hip/hip_runtime.h>

#define BB 8
#define NN 4096
#define CCH 512
#define KK 32
#define CLS 21
#define BN_EPS 1e-3f

#define TPB 512
#define CHUNK 64
#define NBLK (NN / CHUNK)   // 64 -> grid (64,8) = 512 blocks = 2/CU

typedef _Float16 f16;
typedef _Float16 f16x4 __attribute__((ext_vector_type(4)));
typedef _Float16 f16x8 __attribute__((ext_vector_type(8)));
typedef float f32x4 __attribute__((ext_vector_type(4)));

#define NP 36    // wtT row pitch in f16

// LDS carve (bytes)
#define LB_CWB  0                         // f16[2][16][64][8] 32768
#define LB_WTT  32768                     // f16[32][NP]        2304
#define LB_RED  35072                     // f32[6][64][4]      6144
#define LB_XSQ  41216                     // f32[2ch][2m][16]    256
#define LB_CSQ  41472                     // f32[32]             128
#define LB_NSF  41600                     // f32[32]             128
#define LB_WSQ  41728                     // f32[2w][2kt][16]    256
#define LB_TOT  41984

// ws layout (floats)
#define WS_P    0                                  // [NBLK][BB][CCH][KK]
#define WS_WSP  (NBLK * BB * CCH * KK)             // 8388608
#define WS_ENC  (WS_WSP + NBLK * BB * KK)          // 8404992
#define WS_ATTN (WS_ENC + BB * CCH)                // 8409088
#define WS_END  (WS_ATTN + BB * CCH)

template <int CTRL>
__device__ __forceinline__ float dpp_add(float v) {
    int r = __builtin_amdgcn_update_dpp(0, __builtin_bit_cast(int, v),
                                        CTRL, 0xF, 0xF, true);
    return v + __builtin_bit_cast(float, r);
}
template <int CTRL>
__device__ __forceinline__ float dpp_max(float v) {
    int r = __builtin_amdgcn_update_dpp(0, __builtin_bit_cast(int, v),
                                        CTRL, 0xF, 0xF, true);
    return fmaxf(v, __builtin_bit_cast(float, r));
}
__device__ __forceinline__ float rowsum16(float v) {
    v = dpp_add<0x128>(v); v = dpp_add<0x124>(v);
    v = dpp_add<0x122>(v); v = dpp_add<0x121>(v);
    return v;
}
__device__ __forceinline__ float rowmax16(float v) {
    v = dpp_max<0x128>(v); v = dpp_max<0x124>(v);
    v = dpp_max<0x122>(v); v = dpp_max<0x121>(v);
    return v;
}

// ---------------------------------------------------------------------------
// Kernel A (MFMA, no x-staging): fused cross -> softmax -> wx partials.
// cross roles: m=w&1, kt=(w>>1)&1, ch=w>>2.
//   A-frag from global x rows; B-frag from cwB (pre-layout LDS).
// wx: A=wtT[k][n] from LDS, B[k=n][col=c] DIRECT from global x (4x64B per inst).
// ---------------------------------------------------------------------------
__global__ __launch_bounds__(TPB, 2) void enc_mfma(
    const float* __restrict__ x, const float* __restrict__ cw,
    const float* __restrict__ sf, float* __restrict__ ws)
{
    extern __shared__ char sm[];
    f16*   cwB  = (f16*)(sm + LB_CWB);
    f16*   wtT  = (f16*)(sm + LB_WTT);
    float* red  = (float*)(sm + LB_RED);
    float* xsq  = (float*)(sm + LB_XSQ);
    float* csqL = (float*)(sm + LB_CSQ);
    float* nsfL = (float*)(sm + LB_NSF);
    float* wsq  = (float*)(sm + LB_WSQ);

    const int t = threadIdx.x;
    const int b = blockIdx.y;
    const int w = t >> 6;
    const int l = t & 63;
    const int a = l & 15;
    const int g = l >> 4;

    // ---- stage cwB in B-fragment layout (once per block) ----
    for (int si = 0; si < 4; ++si) {
        const int s     = si * 512 + t;        // 0..2047
        const int lane  = s & 63;
        const int cstep = (s >> 6) & 15;
        const int kt    = s >> 10;
        const int k     = (lane & 15) + 16 * kt;
        const int c0    = cstep * 32 + (lane >> 4) * 8;
        f16x8 v;
#pragma unroll
        for (int i = 0; i < 8; ++i) v[i] = (f16)cw[(c0 + i) * KK + k];
        *reinterpret_cast<f16x8*>(cwB + ((size_t)(kt * 16 + cstep) * 64 + lane) * 8) = v;
    }
    // ---- cwsq partials (red used as scratch) ----
    if (t < 256) {
        const int k = t & 31, part = t >> 5;
        float sacc = 0.f;
        for (int c = part * 64; c < part * 64 + 64; ++c) {
            const float v = cw[c * KK + k];
            sacc += v * v;
        }
        red[part * 32 + k] = sacc;
    }
    __syncthreads();
    if (t < 32) {
        float sacc = 0.f;
#pragma unroll
        for (int p = 0; p < 8; ++p) sacc += red[p * 32 + t];
        csqL[t] = sacc;
        nsfL[t] = -sf[t];
    }
    __syncthreads();

    const int m_  = w & 1;
    const int kt_ = (w >> 1) & 1;
    const int ch_ = w >> 2;

    f32x4 acc[4][2];
#pragma unroll
    for (int ct = 0; ct < 4; ++ct)
#pragma unroll
        for (int kt = 0; kt < 2; ++kt) acc[ct][kt] = (f32x4){0.f, 0.f, 0.f, 0.f};
    float wsacc0 = 0.f, wsacc1 = 0.f;

    for (int tile = 0; tile < 2; ++tile) {
        const int n0 = blockIdx.x * CHUNK + tile * 32;

        // ---- cross MFMA: A-frags from global, B-frags from cwB ----
        f32x4 d = {0.f, 0.f, 0.f, 0.f};
        float sq = 0.f;
        const float* xrow = x + (size_t)(b * NN + n0 + 16 * m_ + a) * CCH;
#pragma unroll
        for (int cs = 0; cs < 8; ++cs) {
            const int cstep = ch_ * 8 + cs;
            const int c0 = cstep * 32 + g * 8;
            const float4 u0 = *reinterpret_cast<const float4*>(xrow + c0);
            const float4 u1 = *reinterpret_cast<const float4*>(xrow + c0 + 4);
            if (kt_ == 0)
                sq += u0.x*u0.x + u0.y*u0.y + u0.z*u0.z + u0.w*u0.w
                    + u1.x*u1.x + u1.y*u1.y + u1.z*u1.z + u1.w*u1.w;
            const f16x8 af = {(f16)u0.x, (f16)u0.y, (f16)u0.z, (f16)u0.w,
                              (f16)u1.x, (f16)u1.y, (f16)u1.z, (f16)u1.w};
            const f16x8 bf = *reinterpret_cast<const f16x8*>(
                cwB + ((size_t)(kt_ * 16 + cstep) * 64 + l) * 8);
            d = __builtin_amdgcn_mfma_f32_16x16x32_f16(af, bf, d, 0, 0, 0);
        }
        if (kt_ == 0) {
            sq += __shfl_xor(sq, 16);
            sq += __shfl_xor(sq, 32);
            if (l < 16) xsq[(ch_ * 2 + m_) * 16 + l] = sq;
        }
        if (w >= 2)
            *reinterpret_cast<f32x4*>(red + ((w - 2) * 64 + l) * 4) = d;
        __syncthreads();   // B1: xsq, red ready

        // ---- softmax (waves 0,1; m = w) ----
        if (w < 2) {
            const f32x4 r0 = *reinterpret_cast<const f32x4*>(red + ((w + 2) * 64 + l) * 4); // (m,kt0,ch1)
            const f32x4 r1 = *reinterpret_cast<const f32x4*>(red + ((w    ) * 64 + l) * 4); // (m,kt1,ch0)
            const f32x4 r2 = *reinterpret_cast<const f32x4*>(red + ((w + 4) * 64 + l) * 4); // (m,kt1,ch1)
            const f32x4 d0 = d + r0;
            const f32x4 d1 = r1 + r2;
            const float cq0 = csqL[a],  cq1 = csqL[a + 16];
            const float sf0 = nsfL[a],  sf1 = nsfL[a + 16];
#pragma unroll
            for (int r = 0; r < 4; ++r) {
                const int row = 4 * g + r;
                const float xs = xsq[(0 * 2 + w) * 16 + row]
                               + xsq[(1 * 2 + w) * 16 + row];
                const float l0 = (xs - 2.f * d0[r] + cq0) * sf0;
                const float l1 = (xs - 2.f * d1[r] + cq1) * sf1;
                const float mx = rowmax16(fmaxf(l0, l1));
                const float e0 = __expf(l0 - mx);
                const float e1 = __expf(l1 - mx);
                const float inv = 1.f / rowsum16(e0 + e1);
                const float w0 = e0 * inv, w1 = e1 * inv;
                wsacc0 += w0; wsacc1 += w1;
                const int n = 16 * w + row;
                wtT[(a     ) * NP + n] = (f16)w0;
                wtT[(a + 16) * NP + n] = (f16)w1;
            }
        }
        __syncthreads();   // B2: wtT ready

        // ---- wx MFMA: A from wtT, B direct from global x (f32 -> f16) ----
        {
            union { f16x8 v; f16x4 h[2]; } A0, A1;
            A0.h[0] = *reinterpret_cast<const f16x4*>(wtT + (a     ) * NP + g * 8);
            A0.h[1] = *reinterpret_cast<const f16x4*>(wtT + (a     ) * NP + g * 8 + 4);
            A1.h[0] = *reinterpret_cast<const f16x4*>(wtT + (a + 16) * NP + g * 8);
            A1.h[1] = *reinterpret_cast<const f16x4*>(wtT + (a + 16) * NP + g * 8 + 4);
            const float* xb = x + (size_t)(b * NN + n0 + g * 8) * CCH;
#pragma unroll
            for (int ct = 0; ct < 4; ++ct) {
                const int c = w * 64 + ct * 16 + a;
                f16x8 B;
#pragma unroll
                for (int i = 0; i < 8; ++i)
                    B[i] = (f16)xb[(size_t)i * CCH + c];
                acc[ct][0] = __builtin_amdgcn_mfma_f32_16x16x32_f16(A0.v, B, acc[ct][0], 0, 0, 0);
                acc[ct][1] = __builtin_amdgcn_mfma_f32_16x16x32_f16(A1.v, B, acc[ct][1], 0, 0, 0);
            }
        }
        __syncthreads();   // B3: protect wtT/red/xsq for next tile
    }

    // ---- epilogue: stream wx partials ----
    {
        float* pp = ws + WS_P + ((size_t)(blockIdx.x * BB + b)) * CCH * KK;
#pragma unroll
        for (int ct = 0; ct < 4; ++ct) {
            const int c = w * 64 + ct * 16 + a;
#pragma unroll
            for (int kt = 0; kt < 2; ++kt)
                *reinterpret_cast<f32x4*>(pp + (size_t)c * KK + kt * 16 + g * 4) = acc[ct][kt];
        }
    }
    if (w < 2) {
        float s0 = wsacc0, s1 = wsacc1;
        s0 += __shfl_xor(s0, 16); s0 += __shfl_xor(s0, 32);
        s1 += __shfl_xor(s1, 16); s1 += __shfl_xor(s1, 32);
        if (l < 16) {
            wsq[(w * 2 + 0) * 16 + l] = s0;
            wsq[(w * 2 + 1) * 16 + l] = s1;
        }
    }
    __syncthreads();
    if (t < 32) {
        const int kt = t >> 4, kk_ = t & 15;
        ws[WS_WSP + ((size_t)blockIdx.x * BB + b) * KK + t] =
            wsq[(0 * 2 + kt) * 16 + kk_] + wsq[(1 * 2 + kt) * 16 + kk_];
    }
}

// ---------------------------------------------------------------------------
// Kernel R: reduce partials + enc -> BN -> ReLU -> sum_k => encv
// ---------------------------------------------------------------------------
__global__ __launch_bounds__(256) void reduce_encv(
    float* __restrict__ ws, const float* __restrict__ cw,
    const float* __restrict__ gamma, const float* __restrict__ beta,
    const float* __restrict__ mean, const float* __restrict__ var)
{
    __shared__ float wsum_s[KK];
    const int b  = blockIdx.y;
    const int cs = blockIdx.x;
    const int t  = threadIdx.x;

    if (t < KK) {
        float s = 0.f;
        for (int ch = 0; ch < NBLK; ++ch)
            s += ws[WS_WSP + ((size_t)ch * BB + b) * KK + t];
        wsum_s[t] = s;
    }
    __syncthreads();

    const int cl = t >> 3;
    const int c  = cs * 32 + cl;
    const int kq = t & 7;

    float4 aa = make_float4(0.f, 0.f, 0.f, 0.f);
    for (int ch = 0; ch < NBLK; ++ch) {
        const float4 v = *reinterpret_cast<const float4*>(
            ws + WS_P + (((size_t)ch * BB + b) * CCH + c) * KK + kq * 4);
        aa.x += v.x; aa.y += v.y; aa.z += v.z; aa.w += v.w;
    }
    const float g  = gamma[c] * rsqrtf(var[c] + BN_EPS);
    const float mu = mean[c];
    const float be = beta[c];
    const float4 cv = *reinterpret_cast<const float4*>(cw + c * KK + kq * 4);
    const float4 sv = *reinterpret_cast<const float4*>(&wsum_s[kq * 4]);
    float s = 0.f;
    s += fmaxf((aa.x - cv.x * sv.x - mu) * g + be, 0.f);
    s += fmaxf((aa.y - cv.y * sv.y - mu) * g + be, 0.f);
    s += fmaxf((aa.z - cv.z * sv.z - mu) * g + be, 0.f);
    s += fmaxf((aa.w - cv.w * sv.w - mu) * g + be, 0.f);
    s += __shfl_xor(s, 1);
    s += __shfl_xor(s, 2);
    s += __shfl_xor(s, 4);
    if (kq == 0) ws[WS_ENC + (size_t)b * CCH + c] = s;
}

// ---------------------------------------------------------------------------
// Kernel B2: attn = sigmoid(encv @ w_enc + b_enc) ; se = sigmoid(encv @ w_se + b_se)
// ---------------------------------------------------------------------------
__global__ __launch_bounds__(256) void attn_se_kernel(
    const float* __restrict__ enc, float* __restrict__ attn,
    const float* __restrict__ w_enc, const float* __restrict__ b_enc,
    const float* __restrict__ w_se, const float* __restrict__ b_se,
    float* __restrict__ out)
{
    __shared__ float ev[CCH];
    __shared__ float red[4][64];
    const int b   = blockIdx.y;
    const int cgb = blockIdx.x;
    const int t   = threadIdx.x;
    ev[t]       = enc[(size_t)b * CCH + t];
    ev[t + 256] = enc[(size_t)b * CCH + 256 + t];
    __syncthreads();
    if (cgb < 8) {
        const int c2 = cgb * 64 + (t & 63);
        const int p  = t >> 6;
        float a = 0.f;
#pragma unroll 4
        for (int i = 0; i < 128; ++i) {
            const int c = p * 128 + i;
            a += ev[c] * w_enc[c * CCH + c2];
        }
        red[p][t & 63] = a;
        __syncthreads();
        if (t < 64) {
            const float v = red[0][t] + red[1][t] + red[2][t] + red[3][t]
                          + b_enc[cgb * 64 + t];
            attn[(size_t)b * CCH + cgb * 64 + t] = 1.f / (1.f + __expf(-v));
        }
    } else if (t < 8 * CLS) {
        const int j = t >> 3, p = t & 7;
        float a = 0.f;
        for (int c = p; c < CCH; c += 8) a += ev[c] * w_se[c * CLS + j];
        a += __shfl_xor(a, 1);
        a += __shfl_xor(a, 2);
        a += __shfl_xor(a, 4);
        if (p == 0)
            out[(size_t)BB * NN * CCH + b * CLS + j] =
                1.f / (1.f + __expf(-(a + b_se[j])));
    }
}

// ---------------------------------------------------------------------------
// Kernel C: featuremaps = attn[b,c] * x
// ---------------------------------------------------------------------------
__global__ __launch_bounds__(256) void scale_out(
    const float* __restrict__ x, const float* __restrict__ attn,
    float* __restrict__ out)
{
    const int gid = blockIdx.x * 256 + threadIdx.x;
    const int c4  = (gid & 127) << 2;
#pragma unroll
    for (int b = 0; b < BB; ++b) {
        const size_t f = ((size_t)b << 19) + (size_t)gid;
        const float4 xv = *reinterpret_cast<const float4*>(x + 4 * f);
        const float4 av = *reinterpret_cast<const float4*>(attn + (size_t)b * CCH + c4);
        float4 o;
        o.x = xv.x * av.x; o.y = xv.y * av.y; o.z = xv.z * av.z; o.w = xv.w * av.w;
        *reinterpret_cast<float4*>(out + 4 * f) = o;
    }
}

// ---------------------------------------------------------------------------
extern "C" void kernel_launch(void* const* d_in, const int* in_sizes, int n_in,
                              void* d_out, int out_size, void* d_ws, size_t ws_size,
                              hipStream_t stream)
{
    const float* x     = (const float*)d_in[0];
    const float* cw    = (const float*)d_in[1];
    const float* sf    = (const float*)d_in[2];
    const float* gamma = (const float*)d_in[3];
    const float* beta  = (const float*)d_in[4];
    const float* mean  = (const float*)d_in[5];
    const float* var   = (const float*)d_in[6];
    const float* w_enc = (const float*)d_in[7];
    const float* b_enc = (const float*)d_in[8];
    const float* w_se  = (const float*)d_in[9];
    const float* b_se  = (const float*)d_in[10];
    float* out = (float*)d_out;
    float* ws  = (float*)d_ws;

    enc_mfma<<<dim3(NBLK, BB), TPB, LB_TOT, stream>>>(x, cw, sf, ws);
    reduce_encv<<<dim3(16, BB), 256, 0, stream>>>(ws, cw, gamma, beta, mean, var);
    attn_se_kernel<<<dim3(9, BB), 256, 0, stream>>>(
        ws + WS_ENC, ws + WS_ATTN, w_enc, b_enc, w_se, b_se, out);
    scale_out<<<2048, 256, 0, stream>>>(x, ws + WS_ATTN, out);
}